// Round 8
// baseline (460.717 us; speedup 1.0000x reference)
//
#include <hip/hip_runtime.h>
#include <hip/hip_bf16.h>
#include <stdint.h>

// CachedOPTAttention: B=4, T=1024, D=2048, H=32, HD=64, causal, idx=0.
// FP32 buffers; bf16-class error budget -> bf16 MFMA math inside.
//
// R10:
//   * GEMM tile 128x128 -> 256x128 (8 waves 4Mx2N, 512 thr): acc stays 64
//     VGPR/wave (avoids R5's 256x256 spill), staging 8->6 gl2lds/thread/K-step,
//     A-panel reuse x2. Same XOR LDS swizzle + XCD swizzle (zero conflicts).
//   * Attention K path mirrors the proven V path: kv2b prep kernel builds
//     kb bf16 [b][h][t][d] + vbT bf16 [b][h][d][t]; attention stages BOTH
//     K and V with one pre-swizzled-source global_load_lds per wave. No f32
//     loads, no f2b, no ds_writes in the K/V staging path.
//
// Memory plan (lifetimes audited):
//   d_out: [0,16) xb (dead after QKV) -> vbt ; [16,32) qb (dead after attn)
//          [32,96) cache f32 (final); O GEMM overwrites [0,32) last.
//   d_ws:  [0,24) WT3 (dead after QKV) -> [0,16) kb ; [16,32) ctxb
//          after attn: [0,8) WTo (over dead kb).

typedef __hip_bfloat16 bf16;
typedef unsigned short us;
typedef short s16x8 __attribute__((ext_vector_type(8)));
typedef float f32x4 __attribute__((ext_vector_type(4)));

#define T_SEQ   1024
#define D_MODEL 2048

__device__ inline us f2b(float f) {
    bf16 h = __float2bfloat16(f);
    return *(us*)&h;
}

typedef __attribute__((address_space(1))) const void gas_void;
typedef __attribute__((address_space(3))) void las_void;

__device__ inline void gl2lds16(const void* g, void* l) {
    // per-lane global src; LDS dest = wave-uniform base + lane*16
    __builtin_amdgcn_global_load_lds((gas_void*)g, (las_void*)l, 16, 0, 0);
}

// ---------------------------------------------------------------------------
// x[4096][2048] f32 -> bf16 (linear)
// ---------------------------------------------------------------------------
__global__ __launch_bounds__(256)
void cvtx_kernel(const float* __restrict__ x, us* __restrict__ xb)
{
    const size_t i = ((size_t)blockIdx.x * 256 + threadIdx.x) * 8;
    float4 a = *(const float4*)(x + i);
    float4 b = *(const float4*)(x + i + 4);
    union { uint4 u; us s[8]; } p;
    p.s[0] = f2b(a.x); p.s[1] = f2b(a.y); p.s[2] = f2b(a.z); p.s[3] = f2b(a.w);
    p.s[4] = f2b(b.x); p.s[5] = f2b(b.y); p.s[6] = f2b(b.z); p.s[7] = f2b(b.w);
    *(uint4*)(xb + i) = p.u;
}

// ---------------------------------------------------------------------------
// W[2048][2048] f32 (k-major) -> Wt + z*2048*2048: bf16 [N][K] (k contiguous).
// ---------------------------------------------------------------------------
__global__ __launch_bounds__(256)
void wtrans_kernel(const float* __restrict__ W0, const float* __restrict__ W1,
                   const float* __restrict__ W2, us* __restrict__ Wt)
{
    __shared__ float tile[64][65];
    const int z = blockIdx.z;
    const float* W = (z == 0) ? W0 : (z == 1) ? W1 : W2;
    us* dst = Wt + (size_t)z * D_MODEL * D_MODEL;

    const int tid = threadIdx.x;
    const int k0 = blockIdx.y * 64, n0 = blockIdx.x * 64;

    const int rr = tid >> 4, cc = (tid & 15) * 4;
    #pragma unroll
    for (int i = 0; i < 4; ++i) {
        float4 v = *(const float4*)(W + (size_t)(k0 + rr + i * 16) * D_MODEL + n0 + cc);
        tile[rr + i * 16][cc]     = v.x;
        tile[rr + i * 16][cc + 1] = v.y;
        tile[rr + i * 16][cc + 2] = v.z;
        tile[rr + i * 16][cc + 3] = v.w;
    }
    __syncthreads();

    const int nr = tid >> 3, kc = (tid & 7) * 8;
    #pragma unroll
    for (int i = 0; i < 2; ++i) {
        const int n = nr + i * 32;
        union { uint4 u; us s[8]; } p;
        #pragma unroll
        for (int j = 0; j < 8; ++j) p.s[j] = f2b(tile[kc + j][n]);
        *(uint4*)(dst + (size_t)(n0 + n) * D_MODEL + k0 + kc) = p.u;
    }
}

// ---------------------------------------------------------------------------
// kv2b: slot0 (z even): cache K f32 [b][t][h*64+d] -> kb bf16 [b][h][t][d]
//       (gather-convert, coalesced both sides, no LDS needed);
//       slot1 (z odd): cache V f32 -> vbT bf16 [b][h][d][t] (LDS transpose).
// Grid (16 t-tiles, 32 h, 8 = b*2+slot), 256 threads.
// ---------------------------------------------------------------------------
__global__ __launch_bounds__(256)
void kv2b_kernel(const float* __restrict__ cache, us* __restrict__ kb,
                 us* __restrict__ vbt)
{
    __shared__ float tile[64][65];
    const int t0   = blockIdx.x * 64;
    const int h    = blockIdx.y;
    const int b    = blockIdx.z >> 1;
    const int slot = blockIdx.z & 1;
    const int tid  = threadIdx.x;

    const float* src = cache + ((size_t)(b * 2 + slot) * T_SEQ) * D_MODEL + h * 64;

    if (slot == 0) {
        // K: straight convert, 16 f32 -> 16 us per thread
        const int r = tid >> 2, c = (tid & 3) * 16;
        const float4* s4 = (const float4*)(src + (size_t)(t0 + r) * D_MODEL + c);
        float4 v0 = s4[0], v1 = s4[1], v2 = s4[2], v3 = s4[3];
        const float vv[16] = {v0.x, v0.y, v0.z, v0.w, v1.x, v1.y, v1.z, v1.w,
                              v2.x, v2.y, v2.z, v2.w, v3.x, v3.y, v3.z, v3.w};
        union { uint4 u; us s[8]; } p0, p1;
        #pragma unroll
        for (int i = 0; i < 8; ++i) { p0.s[i] = f2b(vv[i]); p1.s[i] = f2b(vv[8 + i]); }
        us* dst = kb + ((size_t)(b * 32 + h) * 1024 + t0 + r) * 64 + c;
        *(uint4*)(dst)     = p0.u;
        *(uint4*)(dst + 8) = p1.u;
    } else {
        // V: 64x64 LDS transpose -> [d][t]
        const int rr = tid >> 4, cc = (tid & 15) * 4;
        #pragma unroll
        for (int i = 0; i < 4; ++i) {
            float4 v = *(const float4*)(src + (size_t)(t0 + rr + i * 16) * D_MODEL + cc);
            tile[rr + i * 16][cc]     = v.x;
            tile[rr + i * 16][cc + 1] = v.y;
            tile[rr + i * 16][cc + 2] = v.z;
            tile[rr + i * 16][cc + 3] = v.w;
        }
        __syncthreads();
        const int dr = tid >> 3, tc = (tid & 7) * 8;
        #pragma unroll
        for (int i = 0; i < 2; ++i) {
            const int d = dr + i * 32;
            union { uint4 u; us s[8]; } p;
            #pragma unroll
            for (int j = 0; j < 8; ++j) p.s[j] = f2b(tile[tc + j][d]);
            *(uint4*)(vbt + (size_t)((b * 32 + h) * 64 + d) * 1024 + t0 + tc) = p.u;
        }
    }
}

// ---------------------------------------------------------------------------
// GEMM 256x128 (8 waves 4Mx2N, 512 thr, BK=64): C[4096,N] = A(bf16)@Bt^T + b.
// Per wave: 64x64 output (acc 64 VGPR - the R5 spill is structurally avoided).
// Staging: 6 gl2lds/thread/K-step (A 4, B 2), XOR-swizzled via source.
// MODE 0: f32 out (out0), bias b0.                       (O GEMM)
// MODE 3: col routing by n0>>11: 0 -> bf16 qb scaled 1/8 (bias b0),
//         1/2 -> f32 cache slot 0/1 (bias b1/b2).        (QKV GEMM, N=6144)
// ---------------------------------------------------------------------------
template<int MODE>
__global__ __launch_bounds__(512, 2)
void gemm256_kernel(const us* __restrict__ A, const us* __restrict__ Bt,
                    const float* __restrict__ b0, const float* __restrict__ b1,
                    const float* __restrict__ b2,
                    float* __restrict__ out0, float* __restrict__ out1,
                    const int* __restrict__ idxp)
{
    __shared__ __align__(16) us As[256 * 64];   // 32 KB
    __shared__ __align__(16) us Bs[128 * 64];   // 16 KB

    const int tid  = threadIdx.x;
    const int wv   = tid >> 6;       // 0..7
    const int lane = tid & 63;
    const int quad = lane >> 4;
    const int l15  = lane & 15;
    const int wm   = wv >> 1;        // 0..3  (M quarter: rows wm*64..+63)
    const int wn   = wv & 1;         // 0..1  (N half:   cols wn*64..+63)

    // bijective XCD swizzle (grids 768 / 256: nwg % 8 == 0)
    const int gx  = gridDim.x;
    const int nwg = gx * gridDim.y;
    int bid = blockIdx.y * gx + blockIdx.x;
    bid = (bid & 7) * (nwg >> 3) + (bid >> 3);
    const int m0 = (bid / gx) * 256;
    const int n0 = (bid % gx) * 128;

    // staging: 8 rows per gl2lds; lane l -> row (l>>3), src chunk (l&7)^(l>>3)
    const int srow = lane >> 3;
    const int scol = ((lane & 7) ^ srow) * 8;
    const us* aG = A  + (size_t)(m0 + wv * 32 + srow) * D_MODEL + scol;  // 4 calls
    const us* bG = Bt + (size_t)(n0 + wv * 16 + srow) * D_MODEL + scol;  // 2 calls
    us* aL = As + wv * 32 * 64;
    us* bL = Bs + wv * 16 * 64;

    f32x4 acc[4][4];
    #pragma unroll
    for (int mi = 0; mi < 4; ++mi)
        #pragma unroll
        for (int ni = 0; ni < 4; ++ni) acc[mi][ni] = f32x4{0.f, 0.f, 0.f, 0.f};

    const int xr = l15 & 7;
    #define LDA(MI, KK) (*(const s16x8*)(As + (wm * 64 + (MI) * 16 + l15) * 64 \
                          + ((((KK) * 4 + quad) ^ xr) * 8)))
    #define LDB(NI, KK) (*(const s16x8*)(Bs + (wn * 64 + (NI) * 16 + l15) * 64 \
                          + ((((KK) * 4 + quad) ^ xr) * 8)))

    for (int k0 = 0; k0 < D_MODEL; k0 += 64) {
        #pragma unroll
        for (int g = 0; g < 4; ++g)
            gl2lds16(aG + k0 + g * 8 * D_MODEL, aL + g * 512);
        #pragma unroll
        for (int g = 0; g < 2; ++g)
            gl2lds16(bG + k0 + g * 8 * D_MODEL, bL + g * 512);
        __syncthreads();

        #pragma unroll
        for (int kk = 0; kk < 2; ++kk) {
            s16x8 af[4], bfr[4];
            #pragma unroll
            for (int mi = 0; mi < 4; ++mi) af[mi] = LDA(mi, kk);
            #pragma unroll
            for (int ni = 0; ni < 4; ++ni) bfr[ni] = LDB(ni, kk);
            #pragma unroll
            for (int mi = 0; mi < 4; ++mi)
                #pragma unroll
                for (int ni = 0; ni < 4; ++ni)
                    acc[mi][ni] = __builtin_amdgcn_mfma_f32_16x16x32_bf16(
                        af[mi], bfr[ni], acc[mi][ni], 0, 0, 0);
        }
        __syncthreads();
    }
    #undef LDA
    #undef LDB

    const int seg = (MODE == 3) ? (n0 >> 11) : 0;
    const float* bias = (MODE == 3) ? (seg == 0 ? b0 : (seg == 1 ? b1 : b2)) : b0;
    const int idx = (MODE == 3 && seg > 0) ? idxp[0] : 0;

    #pragma unroll
    for (int ni = 0; ni < 4; ++ni) {
        const int col = n0 + wn * 64 + ni * 16 + l15;
        const int cl  = col & (D_MODEL - 1);
        const float bv = bias[cl];
        #pragma unroll
        for (int mi = 0; mi < 4; ++mi) {
            #pragma unroll
            for (int r = 0; r < 4; ++r) {
                const int m = m0 + wm * 64 + mi * 16 + quad * 4 + r;
                const float v = acc[mi][ni][r] + bv;
                if (MODE == 0) {
                    out0[(size_t)m * D_MODEL + cl] = v;
                } else {
                    if (seg == 0) {
                        ((us*)out0)[(size_t)m * D_MODEL + cl] = f2b(v * 0.125f);
                    } else {
                        const int b  = m >> 10;
                        const int tt = ((m & 1023) + idx) & 1023;
                        out1[((size_t)(b * 2 + (seg - 1)) * T_SEQ + tt) * D_MODEL + cl] = v;
                    }
                }
            }
        }
    }
}

// ---------------------------------------------------------------------------
// MFMA flash attention, QBLK=128, double-buffered K/V, both staged via ONE
// pre-swizzled-source global_load_lds per wave per tile (from kb / vbT bf16).
// No f32 loads, no f2b, no ds_writes in staging. One barrier per tile.
// ---------------------------------------------------------------------------
#define LDW 72

__global__ __launch_bounds__(512, 4)
void attn_mfma_kernel(const us* __restrict__ q, const us* __restrict__ kb,
                      const us* __restrict__ vbt, us* __restrict__ ctx)
{
    __shared__ __align__(16) us Qs[128 * LDW];   // 18.4 KB; reused as Ps
    __shared__ __align__(16) us Ks[2][64 * 64];  // 16 KB  [key][d] swizzled
    __shared__ __align__(16) us Vt[2][64 * 64];  // 16 KB  [d][key] swizzled

    const int tid  = threadIdx.x;
    const int wave = tid >> 6;          // 0..7
    const int lane = tid & 63;
    const int quad = lane >> 4;
    const int l15  = lane & 15;
    const int xr   = l15 & 7;

    const int bh = blockIdx.x;          // b*32 + h
    const int b  = bh >> 5;
    const int h  = bh & 31;
    const int qt = 7 - blockIdx.y;      // query tile 0..7 (128 rows each)

    const us* kb_bh = kb  + (size_t)(b * 32 + h) * 65536;   // [1024 t][64 d]
    const us* vb_bh = vbt + (size_t)(b * 32 + h) * 65536;   // [64 d][1024 t]

    // ---- stage Q tile (128q x 64d), bf16 copy ----
    {
        const int qrow = tid >> 2;
        const int qp   = tid & 3;
        const uint4* qg = (const uint4*)(q + (size_t)(b * T_SEQ + qt * 128 + qrow) * D_MODEL
                                           + h * 64 + qp * 16);
        uint4 q0 = qg[0], q1 = qg[1];
        *(uint4*)(Qs + qrow * LDW + qp * 16)     = q0;
        *(uint4*)(Qs + qrow * LDW + qp * 16 + 8) = q1;
    }

    // ---- staging source addresses (pre-swizzled chunk) ----
    const int srow = lane >> 3;                    // 0..7
    const int schk = ((lane & 7) ^ srow) * 8;      // inverse-swizzled 8-elem chunk
    const us* kG = kb_bh + (size_t)(wave * 8 + srow) * 64 + schk;     // +kt*4096
    const us* vG = vb_bh + (size_t)(wave * 8 + srow) * 1024 + schk;   // +kt*64

    const int nkt = 2 * qt + 2;

    // ---- prologue: stage tile 0 into buf 0 ----
    gl2lds16(kG, (us*)Ks[0] + wave * 512);
    gl2lds16(vG, (us*)Vt[0] + wave * 512);
    __syncthreads();   // Q ds_writes + tile-0 gl2lds drained

    // hoist Q A-frags; Qs LDS becomes Ps
    const s16x8 qf0 = *(const s16x8*)(Qs + (wave * 16 + l15) * LDW + quad * 8);
    const s16x8 qf1 = *(const s16x8*)(Qs + (wave * 16 + l15) * LDW + 32 + quad * 8);

    f32x4 oacc[4];
    #pragma unroll
    for (int t = 0; t < 4; ++t) oacc[t] = f32x4{0.f, 0.f, 0.f, 0.f};
    float m_run[4] = {-1e30f, -1e30f, -1e30f, -1e30f};
    float l_run[4] = {0.f, 0.f, 0.f, 0.f};

    for (int kt = 0; kt < nkt; ++kt) {
        const int buf = kt & 1;

        // ---- issue next tile's K+V gl2lds (drained at this tile's barrier) ----
        if (kt + 1 < nkt) {
            gl2lds16(kG + (kt + 1) * 4096, (us*)Ks[buf ^ 1] + wave * 512);
            gl2lds16(vG + (kt + 1) * 64,   (us*)Vt[buf ^ 1] + wave * 512);
        }

        const int kbr = kt * 64 - qt * 128;
        if (kbr < wave * 16 + 16) {          // else fully masked for this wave
            const us* kb_ = (const us*)Ks[buf];
            const us* vb_ = (const us*)Vt[buf];

            // ---- S = Q @ K^T (K reads XOR-swizzled, conflict-free) ----
            f32x4 sacc[4];
            #pragma unroll
            for (int t = 0; t < 4; ++t) sacc[t] = f32x4{0.f, 0.f, 0.f, 0.f};
            #pragma unroll
            for (int t = 0; t < 4; ++t) {
                s16x8 kf0 = *(const s16x8*)(kb_ + (t * 16 + l15) * 64 + ((quad ^ xr) * 8));
                s16x8 kf1 = *(const s16x8*)(kb_ + (t * 16 + l15) * 64 + (((4 + quad) ^ xr) * 8));
                sacc[t] = __builtin_amdgcn_mfma_f32_16x16x32_bf16(qf0, kf0, sacc[t], 0, 0, 0);
                sacc[t] = __builtin_amdgcn_mfma_f32_16x16x32_bf16(qf1, kf1, sacc[t], 0, 0, 0);
            }

            if (kbr + 63 > wave * 16) {      // diagonal-straddling: apply mask
                #pragma unroll
                for (int t = 0; t < 4; ++t) {
                    const int keyl = kbr + t * 16 + l15;
                    #pragma unroll
                    for (int r = 0; r < 4; ++r) {
                        if (keyl > wave * 16 + quad * 4 + r) sacc[t][r] = -1e30f;
                    }
                }
            }

            // ---- online softmax (rows live in lane quads) ----
            float rmax[4];
            #pragma unroll
            for (int r = 0; r < 4; ++r)
                rmax[r] = fmaxf(fmaxf(sacc[0][r], sacc[1][r]), fmaxf(sacc[2][r], sacc[3][r]));
            #pragma unroll
            for (int off = 1; off < 16; off <<= 1) {
                #pragma unroll
                for (int r = 0; r < 4; ++r) rmax[r] = fmaxf(rmax[r], __shfl_xor(rmax[r], off, 16));
            }
            float alpha[4];
            #pragma unroll
            for (int r = 0; r < 4; ++r) {
                const float mnew = fmaxf(m_run[r], rmax[r]);
                alpha[r] = __expf(m_run[r] - mnew);
                m_run[r] = mnew;
            }
            float rsum[4] = {0.f, 0.f, 0.f, 0.f};
            #pragma unroll
            for (int t = 0; t < 4; ++t) {
                #pragma unroll
                for (int r = 0; r < 4; ++r) {
                    const float p = __expf(sacc[t][r] - m_run[r]);
                    sacc[t][r] = p;
                    rsum[r] += p;
                }
            }
            #pragma unroll
            for (int off = 1; off < 16; off <<= 1) {
                #pragma unroll
                for (int r = 0; r < 4; ++r) rsum[r] += __shfl_xor(rsum[r], off, 16);
            }
            #pragma unroll
            for (int r = 0; r < 4; ++r) l_run[r] = l_run[r] * alpha[r] + rsum[r];
            #pragma unroll
            for (int t = 0; t < 4; ++t) {
                #pragma unroll
                for (int r = 0; r < 4; ++r) oacc[t][r] *= alpha[r];
            }

            // ---- P -> LDS (per-wave private 16-row slab of reused Qs) ----
            #pragma unroll
            for (int t = 0; t < 4; ++t) {
                #pragma unroll
                for (int r = 0; r < 4; ++r)
                    Qs[(wave * 16 + quad * 4 + r) * LDW + t * 16 + l15] = f2b(sacc[t][r]);
            }
            // same-wave write->read ordered by lgkmcnt

            // ---- O += P @ V^T (V reads XOR-swizzled, conflict-free) ----
            s16x8 pf0 = *(const s16x8*)(Qs + (wave * 16 + l15) * LDW + quad * 8);
            s16x8 pf1 = *(const s16x8*)(Qs + (wave * 16 + l15) * LDW + 32 + quad * 8);
            #pragma unroll
            for (int t = 0; t < 4; ++t) {
                s16x8 vf0 = *(const s16x8*)(vb_ + (t * 16 + l15) * 64 + ((quad ^ xr) * 8));
                s16x8 vf1 = *(const s16x8*)(vb_ + (t * 16 + l15) * 64 + (((4 + quad) ^ xr) * 8));
                oacc[t] = __builtin_amdgcn_mfma_f32_16x16x32_bf16(pf0, vf0, oacc[t], 0, 0, 0);
                oacc[t] = __builtin_amdgcn_mfma_f32_16x16x32_bf16(pf1, vf1, oacc[t], 0, 0, 0);
            }
        }

        __syncthreads();   // drains next-tile gl2lds (vmcnt) + P writes; flips buffers
    }

    // ---- epilogue: ctx (bf16) = O / l ----
    float invl[4];
    #pragma unroll
    for (int r = 0; r < 4; ++r) invl[r] = 1.0f / l_run[r];
    #pragma unroll
    for (int r = 0; r < 4; ++r) {
        const int qrow = qt * 128 + wave * 16 + quad * 4 + r;
        us* orow = ctx + (size_t)(b * T_SEQ + qrow) * D_MODEL + h * 64;
        #pragma unroll
        for (int t = 0; t < 4; ++t) orow[t * 16 + l15] = f2b(oacc[t][r] * invl[r]);
    }
}

// ---------------------------------------------------------------------------
extern "C" void kernel_launch(void* const* d_in, const int* in_sizes, int n_in,
                              void* d_out, int out_size, void* d_ws, size_t ws_size,
                              hipStream_t stream)
{
    const float* x    = (const float*)d_in[0];
    const int*   idxp = (const int*)d_in[3];
    const float* Wq   = (const float*)d_in[4];
    const float* bq   = (const float*)d_in[5];
    const float* Wk   = (const float*)d_in[6];
    const float* bk   = (const float*)d_in[7];
    const float* Wv   = (const float*)d_in[8];
    const float* bv   = (const float*)d_in[9];
    const float* Wo   = (const float*)d_in[10];
    const float* bo   = (const float*)d_in[11];

    float* out      = (float*)d_out;
    us*    xb       = (us*)d_out;                                   // [0,16MB)
    us*    vbt      = (us*)d_out;                                   // [0,16MB) after QKV
    us*    qb       = (us*)d_out + (size_t)8 * 1024 * 1024;         // [16,32MB)
    float* cacheOut = out + (size_t)4 * T_SEQ * D_MODEL;            // [32,96MB)

    us* WT3  = (us*)d_ws;                                           // [0,24MB)
    us* kb   = (us*)d_ws;                                           // [0,16MB)  after QKV
    us* ctxb = (us*)d_ws + (size_t)8 * 1024 * 1024;                 // [16,32MB) after QKV
    us* WTo  = (us*)d_ws;                                           // [0,8MB)   after attn

    const dim3 tb(256);

    cvtx_kernel<<<dim3(4096), tb, 0, stream>>>(x, xb);
    wtrans_kernel<<<dim3(32, 32, 3), tb, 0, stream>>>(Wq, Wk, Wv, WT3);

    // fused QKV: N = 6144, 256x128 tiles -> 48 x 16 = 768 blocks
    gemm256_kernel<3><<<dim3(48, 16), dim3(512), 0, stream>>>(
        xb, WT3, bq, bk, bv, (float*)qb, cacheOut, idxp);

    // cache K/V f32 -> kb bf16 [b][h][t][d] + vbT bf16 [b][h][d][t]
    kv2b_kernel<<<dim3(16, 32, 8), tb, 0, stream>>>(cacheOut, kb, vbt);

    attn_mfma_kernel<<<dim3(128, 8), dim3(512), 0, stream>>>(qb, kb, vbt, ctxb);

    wtrans_kernel<<<dim3(32, 32, 1), tb, 0, stream>>>(Wo, Wo, Wo, WTo);

    // O GEMM: N = 2048 -> 16 x 16 = 256 blocks
    gemm256_kernel<0><<<dim3(16, 16), dim3(512), 0, stream>>>(
        ctxb, WTo, bo, nullptr, nullptr, out, nullptr, nullptr);
}

// Round 9
// 449.038 us; speedup vs baseline: 1.0260x; 1.0260x over previous
//
#include <hip/hip_runtime.h>
#include <hip/hip_bf16.h>
#include <stdint.h>

// CachedOPTAttention: B=4, T=1024, D=2048, H=32, HD=64, causal, idx=0.
// FP32 buffers; bf16-class error budget -> bf16 MFMA math inside.
//
// R11: R9 pipeline (best measured: QKV 128^2 @124us, v2t, O 128^2) with the
// attention reverted to the R1-measured-85us QBLK=64 / 256-thr / 4-wave shape
// (cross-round accounting shows the QBLK=128 attn was ~2x slower than the
// QBLK=64 one it replaced), upgraded with this session's proven staging:
//   * V: one pre-swizzled-source global_load_lds pair per wave from vbT
//     (zero-conflict XOR reads) - no f32 loads/convert/transpose in-kernel.
//   * K: T14 issue-early f32 loads / convert+ds_write-late, double-buffered.
//   * ONE barrier per tile. LDS 43KB -> 3 blocks/CU (12 waves).
//
// Memory plan (identical to R9):
//   d_out: [0,16) xb (dead after QKV) -> vbt ; [16,32) qb (dead after attn)
//          [32,96) cache f32 (final); O GEMM overwrites [0,32) last.
//   d_ws:  [0,24) WT3 (dead after QKV) -> unused; [16,32) ctxb
//          after attn: [0,8) WTo.

typedef __hip_bfloat16 bf16;
typedef unsigned short us;
typedef short s16x8 __attribute__((ext_vector_type(8)));
typedef float f32x4 __attribute__((ext_vector_type(4)));

#define T_SEQ   1024
#define D_MODEL 2048

__device__ inline us f2b(float f) {
    bf16 h = __float2bfloat16(f);
    return *(us*)&h;
}

typedef __attribute__((address_space(1))) const void gas_void;
typedef __attribute__((address_space(3))) void las_void;

__device__ inline void gl2lds16(const void* g, void* l) {
    // per-lane global src; LDS dest = wave-uniform base + lane*16
    __builtin_amdgcn_global_load_lds((gas_void*)g, (las_void*)l, 16, 0, 0);
}

// ---------------------------------------------------------------------------
// x[4096][2048] f32 -> bf16 (linear)
// ---------------------------------------------------------------------------
__global__ __launch_bounds__(256)
void cvtx_kernel(const float* __restrict__ x, us* __restrict__ xb)
{
    const size_t i = ((size_t)blockIdx.x * 256 + threadIdx.x) * 8;
    float4 a = *(const float4*)(x + i);
    float4 b = *(const float4*)(x + i + 4);
    union { uint4 u; us s[8]; } p;
    p.s[0] = f2b(a.x); p.s[1] = f2b(a.y); p.s[2] = f2b(a.z); p.s[3] = f2b(a.w);
    p.s[4] = f2b(b.x); p.s[5] = f2b(b.y); p.s[6] = f2b(b.z); p.s[7] = f2b(b.w);
    *(uint4*)(xb + i) = p.u;
}

// ---------------------------------------------------------------------------
// W[2048][2048] f32 (k-major) -> Wt + z*2048*2048: bf16 [N][K] (k contiguous).
// ---------------------------------------------------------------------------
__global__ __launch_bounds__(256)
void wtrans_kernel(const float* __restrict__ W0, const float* __restrict__ W1,
                   const float* __restrict__ W2, us* __restrict__ Wt)
{
    __shared__ float tile[64][65];
    const int z = blockIdx.z;
    const float* W = (z == 0) ? W0 : (z == 1) ? W1 : W2;
    us* dst = Wt + (size_t)z * D_MODEL * D_MODEL;

    const int tid = threadIdx.x;
    const int k0 = blockIdx.y * 64, n0 = blockIdx.x * 64;

    const int rr = tid >> 4, cc = (tid & 15) * 4;
    #pragma unroll
    for (int i = 0; i < 4; ++i) {
        float4 v = *(const float4*)(W + (size_t)(k0 + rr + i * 16) * D_MODEL + n0 + cc);
        tile[rr + i * 16][cc]     = v.x;
        tile[rr + i * 16][cc + 1] = v.y;
        tile[rr + i * 16][cc + 2] = v.z;
        tile[rr + i * 16][cc + 3] = v.w;
    }
    __syncthreads();

    const int nr = tid >> 3, kc = (tid & 7) * 8;
    #pragma unroll
    for (int i = 0; i < 2; ++i) {
        const int n = nr + i * 32;
        union { uint4 u; us s[8]; } p;
        #pragma unroll
        for (int j = 0; j < 8; ++j) p.s[j] = f2b(tile[kc + j][n]);
        *(uint4*)(dst + (size_t)(n0 + n) * D_MODEL + k0 + kc) = p.u;
    }
}

// ---------------------------------------------------------------------------
// v2t: cache slot1 f32 [b][t][h*64+d] -> vbT bf16 [b][h][d][t].
// 64t x 64d LDS tile; coalesced both sides. Grid (16, 32, 4), 256 thr.
// ---------------------------------------------------------------------------
__global__ __launch_bounds__(256)
void v2t_kernel(const float* __restrict__ cache, us* __restrict__ vbt)
{
    __shared__ float tile[64][65];
    const int t0 = blockIdx.x * 64;
    const int h  = blockIdx.y;
    const int b  = blockIdx.z;

    const float* src = cache + ((size_t)(b * 2 + 1) * T_SEQ) * D_MODEL + h * 64;

    const int tid = threadIdx.x;
    const int rr = tid >> 4, cc = (tid & 15) * 4;
    #pragma unroll
    for (int i = 0; i < 4; ++i) {
        float4 v = *(const float4*)(src + (size_t)(t0 + rr + i * 16) * D_MODEL + cc);
        tile[rr + i * 16][cc]     = v.x;
        tile[rr + i * 16][cc + 1] = v.y;
        tile[rr + i * 16][cc + 2] = v.z;
        tile[rr + i * 16][cc + 3] = v.w;
    }
    __syncthreads();

    const int dr = tid >> 3, tc = (tid & 7) * 8;
    #pragma unroll
    for (int i = 0; i < 2; ++i) {
        const int d = dr + i * 32;
        union { uint4 u; us s[8]; } p;
        #pragma unroll
        for (int j = 0; j < 8; ++j) p.s[j] = f2b(tile[tc + j][d]);
        *(uint4*)(vbt + (size_t)((b * 32 + h) * 64 + d) * 1024 + t0 + tc) = p.u;
    }
}

// ---------------------------------------------------------------------------
// GEMM (m97 structure, BK=64, R6/R9-proven): C[4096, N] = A(bf16)@Bt^T + bias.
// XOR-swizzled LDS (zero bank conflicts), bijective XCD block swizzle.
// MODE 0: f32 out (out0), bias b0.                       (O GEMM)
// MODE 3: col routing by n0>>11: 0 -> bf16 qb scaled 1/8 (bias b0),
//         1/2 -> f32 cache slot 0/1 (bias b1/b2).        (QKV GEMM, N=6144)
// ---------------------------------------------------------------------------
template<int MODE>
__global__ __launch_bounds__(256, 3)
void gemm128_kernel(const us* __restrict__ A, const us* __restrict__ Bt,
                    const float* __restrict__ b0, const float* __restrict__ b1,
                    const float* __restrict__ b2,
                    float* __restrict__ out0, float* __restrict__ out1,
                    const int* __restrict__ idxp)
{
    __shared__ __align__(16) us As[128 * 64];   // 16 KB
    __shared__ __align__(16) us Bs[128 * 64];   // 16 KB

    const int tid  = threadIdx.x;
    const int wv   = tid >> 6;       // 0..3
    const int lane = tid & 63;
    const int quad = lane >> 4;
    const int l15  = lane & 15;
    const int wm   = wv >> 1;        // 0..1
    const int wn   = wv & 1;         // 0..1

    // bijective XCD swizzle (grids 1536 / 512: nwg % 8 == 0)
    const int gx  = gridDim.x;
    const int nwg = gx * gridDim.y;
    int bid = blockIdx.y * gx + blockIdx.x;
    bid = (bid & 7) * (nwg >> 3) + (bid >> 3);
    const int m0 = (bid / gx) * 128;
    const int n0 = (bid % gx) * 128;

    // staging: 8 rows per gl2lds call; lane l -> row (l>>3), chunk (l&7)^(l>>3)
    const int srow = lane >> 3;
    const int scol = ((lane & 7) ^ srow) * 8;
    const us* aG = A  + (size_t)(m0 + wv * 32 + srow) * D_MODEL + scol;
    const us* bG = Bt + (size_t)(n0 + wv * 32 + srow) * D_MODEL + scol;
    us* aL = As + wv * 32 * 64;
    us* bL = Bs + wv * 32 * 64;

    f32x4 acc[4][4];
    #pragma unroll
    for (int mi = 0; mi < 4; ++mi)
        #pragma unroll
        for (int ni = 0; ni < 4; ++ni) acc[mi][ni] = f32x4{0.f, 0.f, 0.f, 0.f};

    const int xr = l15 & 7;
    #define LDA(MI, KK) (*(const s16x8*)(As + (wm * 64 + (MI) * 16 + l15) * 64 \
                          + ((((KK) * 4 + quad) ^ xr) * 8)))
    #define LDB(NI, KK) (*(const s16x8*)(Bs + (wn * 64 + (NI) * 16 + l15) * 64 \
                          + ((((KK) * 4 + quad) ^ xr) * 8)))

    for (int k0 = 0; k0 < D_MODEL; k0 += 64) {
        #pragma unroll
        for (int g = 0; g < 4; ++g) {
            gl2lds16(aG + k0 + g * 8 * D_MODEL, aL + g * 512);
            gl2lds16(bG + k0 + g * 8 * D_MODEL, bL + g * 512);
        }
        __syncthreads();

        #pragma unroll
        for (int kk = 0; kk < 2; ++kk) {
            s16x8 af[4], bfr[4];
            #pragma unroll
            for (int mi = 0; mi < 4; ++mi) af[mi] = LDA(mi, kk);
            #pragma unroll
            for (int ni = 0; ni < 4; ++ni) bfr[ni] = LDB(ni, kk);
            #pragma unroll
            for (int mi = 0; mi < 4; ++mi)
                #pragma unroll
                for (int ni = 0; ni < 4; ++ni)
                    acc[mi][ni] = __builtin_amdgcn_mfma_f32_16x16x32_bf16(
                        af[mi], bfr[ni], acc[mi][ni], 0, 0, 0);
        }
        __syncthreads();
    }
    #undef LDA
    #undef LDB

    const int seg = (MODE == 3) ? (n0 >> 11) : 0;
    const float* bias = (MODE == 3) ? (seg == 0 ? b0 : (seg == 1 ? b1 : b2)) : b0;
    const int idx = (MODE == 3 && seg > 0) ? idxp[0] : 0;

    #pragma unroll
    for (int ni = 0; ni < 4; ++ni) {
        const int col = n0 + wn * 64 + ni * 16 + l15;
        const int cl  = col & (D_MODEL - 1);
        const float bv = bias[cl];
        #pragma unroll
        for (int mi = 0; mi < 4; ++mi) {
            #pragma unroll
            for (int r = 0; r < 4; ++r) {
                const int m = m0 + wm * 64 + mi * 16 + quad * 4 + r;
                const float v = acc[mi][ni][r] + bv;
                if (MODE == 0) {
                    out0[(size_t)m * D_MODEL + cl] = v;
                } else {
                    if (seg == 0) {
                        ((us*)out0)[(size_t)m * D_MODEL + cl] = f2b(v * 0.125f);
                    } else {
                        const int b  = m >> 10;
                        const int tt = ((m & 1023) + idx) & 1023;
                        out1[((size_t)(b * 2 + (seg - 1)) * T_SEQ + tt) * D_MODEL + cl] = v;
                    }
                }
            }
        }
    }
}

// ---------------------------------------------------------------------------
// MFMA flash attention, QBLK=64 (R1-measured-85us shape), 256 thr = 4 waves,
// each wave owns 16 q-rows. Grid (128 bh, 16 qt; heavy-first). Per 64-key
// tile, double-buffered, ONE barrier:
//   issue-early: next V (2 gl2lds/wave from vbT, pre-swizzled source) +
//                next K (f32 -> 16 regs);
//   compute buf: QK MFMA -> online softmax -> P via Qs-reuse -> PV MFMA
//                (V reads XOR-swizzled, conflict-free);
//   write-late:  K f2b + 2 ds_write into buf^1; barrier.
// ---------------------------------------------------------------------------
#define LDW 72

__global__ __launch_bounds__(256, 3)
void attn_mfma_kernel(const us* __restrict__ q, const float* __restrict__ cache,
                      const us* __restrict__ vbt, us* __restrict__ ctx)
{
    __shared__ __align__(16) us Qs[64 * LDW];    // 9.2 KB; reused as Ps
    __shared__ __align__(16) us Ks[2][64 * LDW]; // 18.4 KB [key][d]
    __shared__ __align__(16) us Vt[2][64 * 64];  // 16 KB   [d][key] swizzled
                                                 // total 43.6 KB -> 3 blk/CU
    const int tid  = threadIdx.x;
    const int wave = tid >> 6;          // 0..3
    const int lane = tid & 63;
    const int quad = lane >> 4;
    const int l15  = lane & 15;
    const int xr   = l15 & 7;

    const int bh = blockIdx.x;          // b*32 + h
    const int b  = bh >> 5;
    const int h  = bh & 31;
    const int qt = 15 - blockIdx.y;     // query tile 0..15 (64 rows each)

    const float* kbase = cache + ((size_t)(b * 2 + 0) * T_SEQ) * D_MODEL + h * 64;
    const us* vb_bh = vbt + (size_t)(b * 32 + h) * 65536;   // [64 d][1024 t]

    // ---- staging coords ----
    const int ksrow = tid >> 2;                  // 0..63 (K row)
    const int kpart = (tid & 3) * 16;            // 16-d chunk base
    const int vrow  = lane >> 3;                 // 0..7 (d-row within gl2lds)
    const int vchk  = ((lane & 7) ^ vrow) * 8;   // pre-swizzled key-chunk
    // wave stages d-rows [wave*16, wave*16+16): 2 gl2lds of 8 rows each
    const us* vG0 = vb_bh + (size_t)(wave * 16 + vrow) * 1024 + vchk;
    const us* vG1 = vb_bh + (size_t)(wave * 16 + 8 + vrow) * 1024 + vchk;

    // ---- stage Q tile (64q x 64d bf16 copy) + tile 0 of K (f32) & V ----
    {
        const uint4* qg = (const uint4*)(q + (size_t)(b * T_SEQ + qt * 64 + ksrow) * D_MODEL
                                           + h * 64 + kpart);
        uint4 q0 = qg[0], q1 = qg[1];
        *(uint4*)(Qs + ksrow * LDW + kpart)     = q0;
        *(uint4*)(Qs + ksrow * LDW + kpart + 8) = q1;
    }
    gl2lds16(vG0, (us*)Vt[0] + wave * 1024);
    gl2lds16(vG1, (us*)Vt[0] + wave * 1024 + 512);
    {
        const float4* kg = (const float4*)(kbase + (size_t)ksrow * D_MODEL + kpart);
        float4 k0 = kg[0], k1 = kg[1], k2 = kg[2], k3 = kg[3];
        const float kv[16] = {k0.x, k0.y, k0.z, k0.w, k1.x, k1.y, k1.z, k1.w,
                              k2.x, k2.y, k2.z, k2.w, k3.x, k3.y, k3.z, k3.w};
        union { uint4 u; us s[8]; } p0, p1;
        #pragma unroll
        for (int i = 0; i < 8; ++i) { p0.s[i] = f2b(kv[i]); p1.s[i] = f2b(kv[8 + i]); }
        *(uint4*)(&Ks[0][ksrow * LDW + kpart])     = p0.u;
        *(uint4*)(&Ks[0][ksrow * LDW + kpart + 8]) = p1.u;
    }
    __syncthreads();   // Q + tile-0 K ds_writes + V gl2lds drained

    // hoist Q A-frags; Qs LDS becomes Ps
    const s16x8 qf0 = *(const s16x8*)(Qs + (wave * 16 + l15) * LDW + quad * 8);
    const s16x8 qf1 = *(const s16x8*)(Qs + (wave * 16 + l15) * LDW + 32 + quad * 8);

    f32x4 oacc[4];
    #pragma unroll
    for (int t = 0; t < 4; ++t) oacc[t] = f32x4{0.f, 0.f, 0.f, 0.f};
    float m_run[4] = {-1e30f, -1e30f, -1e30f, -1e30f};
    float l_run[4] = {0.f, 0.f, 0.f, 0.f};

    for (int kt = 0; kt <= qt; ++kt) {
        const int buf = kt & 1;
        const bool more = (kt < qt);

        // ---- T14 issue-early: next V gl2lds + next K f32 -> regs ----
        float4 nk0, nk1, nk2, nk3;
        if (more) {
            gl2lds16(vG0 + (kt + 1) * 64, (us*)Vt[buf ^ 1] + wave * 1024);
            gl2lds16(vG1 + (kt + 1) * 64, (us*)Vt[buf ^ 1] + wave * 1024 + 512);
            const float4* kg = (const float4*)(kbase
                + (size_t)((kt + 1) * 64 + ksrow) * D_MODEL + kpart);
            nk0 = kg[0]; nk1 = kg[1]; nk2 = kg[2]; nk3 = kg[3];
        }

        {
            const us* kb_ = (const us*)Ks[buf];
            const us* vb_ = (const us*)Vt[buf];

            // ---- S = Q @ K^T : 16 queries x 64 keys per wave ----
            f32x4 sacc[4];
            #pragma unroll
            for (int t = 0; t < 4; ++t) sacc[t] = f32x4{0.f, 0.f, 0.f, 0.f};
            #pragma unroll
            for (int t = 0; t < 4; ++t) {
                s16x8 kf0 = *(const s16x8*)(kb_ + (t * 16 + l15) * LDW + quad * 8);
                s16x8 kf1 = *(const s16x8*)(kb_ + (t * 16 + l15) * LDW + 32 + quad * 8);
                sacc[t] = __builtin_amdgcn_mfma_f32_16x16x32_bf16(qf0, kf0, sacc[t], 0, 0, 0);
                sacc[t] = __builtin_amdgcn_mfma_f32_16x16x32_bf16(qf1, kf1, sacc[t], 0, 0, 0);
            }

            // causal mask: only the diagonal tile (key base == q-tile base)
            if (kt == qt) {
                #pragma unroll
                for (int t = 0; t < 4; ++t) {
                    const int keyl = t * 16 + l15;
                    #pragma unroll
                    for (int r = 0; r < 4; ++r) {
                        if (keyl > wave * 16 + quad * 4 + r) sacc[t][r] = -1e30f;
                    }
                }
            }

            // ---- online softmax (rows live in lane quads) ----
            float rmax[4];
            #pragma unroll
            for (int r = 0; r < 4; ++r)
                rmax[r] = fmaxf(fmaxf(sacc[0][r], sacc[1][r]), fmaxf(sacc[2][r], sacc[3][r]));
            #pragma unroll
            for (int off = 1; off < 16; off <<= 1) {
                #pragma unroll
                for (int r = 0; r < 4; ++r) rmax[r] = fmaxf(rmax[r], __shfl_xor(rmax[r], off, 16));
            }
            float alpha[4];
            #pragma unroll
            for (int r = 0; r < 4; ++r) {
                const float mnew = fmaxf(m_run[r], rmax[r]);
                alpha[r] = __expf(m_run[r] - mnew);
                m_run[r] = mnew;
            }
            float rsum[4] = {0.f, 0.f, 0.f, 0.f};
            #pragma unroll
            for (int t = 0; t < 4; ++t) {
                #pragma unroll
                for (int r = 0; r < 4; ++r) {
                    const float p = __expf(sacc[t][r] - m_run[r]);
                    sacc[t][r] = p;
                    rsum[r] += p;
                }
            }
            #pragma unroll
            for (int off = 1; off < 16; off <<= 1) {
                #pragma unroll
                for (int r = 0; r < 4; ++r) rsum[r] += __shfl_xor(rsum[r], off, 16);
            }
            #pragma unroll
            for (int r = 0; r < 4; ++r) l_run[r] = l_run[r] * alpha[r] + rsum[r];
            #pragma unroll
            for (int t = 0; t < 4; ++t) {
                #pragma unroll
                for (int r = 0; r < 4; ++r) oacc[t][r] *= alpha[r];
            }

            // ---- P -> LDS (per-wave private 16-row slab of reused Qs) ----
            #pragma unroll
            for (int t = 0; t < 4; ++t) {
                #pragma unroll
                for (int r = 0; r < 4; ++r)
                    Qs[(wave * 16 + quad * 4 + r) * LDW + t * 16 + l15] = f2b(sacc[t][r]);
            }
            // same-wave write->read ordered by lgkmcnt

            // ---- O += P @ V^T (V reads XOR-swizzled, conflict-free) ----
            s16x8 pf0 = *(const s16x8*)(Qs + (wave * 16 + l15) * LDW + quad * 8);
            s16x8 pf1 = *(const s16x8*)(Qs + (wave * 16 + l15) * LDW + 32 + quad * 8);
            #pragma unroll
            for (int t = 0; t < 4; ++t) {
                s16x8 vf0 = *(const s16x8*)(vb_ + (t * 16 + l15) * 64 + ((quad ^ xr) * 8));
                s16x8 vf1 = *(const s16x8*)(vb_ + (t * 16 + l15) * 64 + (((4 + quad) ^ xr) * 8));
                oacc[t] = __builtin_amdgcn_mfma_f32_16x16x32_bf16(pf0, vf0, oacc[t], 0, 0, 0);
                oacc[t] = __builtin_amdgcn_mfma_f32_16x16x32_bf16(pf1, vf1, oacc[t], 0, 0, 0);
            }
        }

        // ---- T14 write-late: K convert + ds_write into buf^1 ----
        if (more) {
            const float kv[16] = {nk0.x, nk0.y, nk0.z, nk0.w, nk1.x, nk1.y, nk1.z, nk1.w,
                                  nk2.x, nk2.y, nk2.z, nk2.w, nk3.x, nk3.y, nk3.z, nk3.w};
            union { uint4 u; us s[8]; } p0, p1;
            #pragma unroll
            for (int i = 0; i < 8; ++i) { p0.s[i] = f2b(kv[i]); p1.s[i] = f2b(kv[8 + i]); }
            *(uint4*)(&Ks[buf ^ 1][ksrow * LDW + kpart])     = p0.u;
            *(uint4*)(&Ks[buf ^ 1][ksrow * LDW + kpart + 8]) = p1.u;
        }
        __syncthreads();   // drains gl2lds (vmcnt) + ds_writes; flips buffers
    }

    // ---- epilogue: ctx (bf16) = O / l ----
    float invl[4];
    #pragma unroll
    for (int r = 0; r < 4; ++r) invl[r] = 1.0f / l_run[r];
    #pragma unroll
    for (int r = 0; r < 4; ++r) {
        const int qrow = qt * 64 + wave * 16 + quad * 4 + r;
        us* orow = ctx + (size_t)(b * T_SEQ + qrow) * D_MODEL + h * 64;
        #pragma unroll
        for (int t = 0; t < 4; ++t) orow[t * 16 + l15] = f2b(oacc[t][r] * invl[r]);
    }
}

// ---------------------------------------------------------------------------
extern "C" void kernel_launch(void* const* d_in, const int* in_sizes, int n_in,
                              void* d_out, int out_size, void* d_ws, size_t ws_size,
                              hipStream_t stream)
{
    const float* x    = (const float*)d_in[0];
    const int*   idxp = (const int*)d_in[3];
    const float* Wq   = (const float*)d_in[4];
    const float* bq   = (const float*)d_in[5];
    const float* Wk   = (const float*)d_in[6];
    const float* bk   = (const float*)d_in[7];
    const float* Wv   = (const float*)d_in[8];
    const float* bv   = (const float*)d_in[9];
    const float* Wo   = (const float*)d_in[10];
    const float* bo   = (const float*)d_in[11];

    float* out      = (float*)d_out;
    us*    xb       = (us*)d_out;                                   // [0,16MB)
    us*    vbt      = (us*)d_out;                                   // [0,16MB) after QKV
    us*    qb       = (us*)d_out + (size_t)8 * 1024 * 1024;         // [16,32MB)
    float* cacheOut = out + (size_t)4 * T_SEQ * D_MODEL;            // [32,96MB)

    us* WT3  = (us*)d_ws;                                           // [0,24MB)
    us* ctxb = (us*)d_ws + (size_t)8 * 1024 * 1024;                 // [16,32MB) after QKV
    us* WTo  = (us*)d_ws;                                           // [0,8MB)   after attn

    const dim3 tb(256);

    cvtx_kernel<<<dim3(4096), tb, 0, stream>>>(x, xb);
    wtrans_kernel<<<dim3(32, 32, 3), tb, 0, stream>>>(Wq, Wk, Wv, WT3);

    // fused QKV: N = 6144 -> 48 x 32 = 1536 blocks (R6/R9-proven, 824 TF)
    gemm128_kernel<3><<<dim3(48, 32), tb, 0, stream>>>(
        xb, WT3, bq, bk, bv, (float*)qb, cacheOut, idxp);

    // cache slot1 f32 -> vbT bf16 (coalesced LDS-tiled transpose)
    v2t_kernel<<<dim3(16, 32, 4), tb, 0, stream>>>(cacheOut, vbt);

    // attention: QBLK=64, 4 waves, grid (128 bh, 16 qt)
    attn_mfma_kernel<<<dim3(128, 16), tb, 0, stream>>>(qb, cacheOut, vbt, ctxb);

    wtrans_kernel<<<dim3(32, 32, 1), tb, 0, stream>>>(Wo, Wo, Wo, WTo);

    // O GEMM: N = 2048 -> 16 x 32 = 512 blocks
    gemm128_kernel<0><<<dim3(16, 32), tb, 0, stream>>>(
        ctxb, WTo, bo, nullptr, nullptr, out, nullptr, nullptr);
}